// Round 2
// baseline (195.933 us; speedup 1.0000x reference)
//
#include <hip/hip_runtime.h>
#include <hip/hip_bf16.h>

#define BS   8192
#define DIM  768
#define TILE 128
#define BK   128   // one scaled-MFMA K per iteration; 6 iterations total

typedef float f32x4 __attribute__((ext_vector_type(4)));
typedef int   i32x4 __attribute__((ext_vector_type(4)));
typedef int   i32x8 __attribute__((ext_vector_type(8)));

__device__ __forceinline__ void async16(const void* g, void* l) {
    __builtin_amdgcn_global_load_lds(
        (const __attribute__((address_space(1))) unsigned int*)g,
        (__attribute__((address_space(3))) unsigned int*)l,
        16, 0, 0);
}

// One wave per row: L2-norm both embeddings, emit fp8 e4m3, diag sim in fp32.
// Blocks 0..63 also zero rowsum/colsum (replaces the hipMemsetAsync dispatch).
__global__ __launch_bounds__(256) void normalize_kernel(
    const float* __restrict__ text, const float* __restrict__ ctr,
    unsigned char* __restrict__ tq, unsigned char* __restrict__ cq,
    float* __restrict__ sim, float* __restrict__ rowsum, float* __restrict__ colsum) {
    if (blockIdx.x < 64) {
        const int i = blockIdx.x * 256 + threadIdx.x;   // covers 16384 = 2*BS
        rowsum[i] = 0.f;
        colsum[i] = 0.f;
    }
    const int lane = threadIdx.x & 63;
    const int row  = blockIdx.x * 4 + (threadIdx.x >> 6);
    const size_t base = (size_t)row * DIM;

    float4 t[3], c[3];
    float st = 0.f, sc = 0.f, sd = 0.f;
#pragma unroll
    for (int i = 0; i < 3; ++i) {
        t[i] = *(const float4*)&text[base + lane * 4 + i * 256];
        c[i] = *(const float4*)&ctr [base + lane * 4 + i * 256];
        st += t[i].x*t[i].x + t[i].y*t[i].y + t[i].z*t[i].z + t[i].w*t[i].w;
        sc += c[i].x*c[i].x + c[i].y*c[i].y + c[i].z*c[i].z + c[i].w*c[i].w;
        sd += t[i].x*c[i].x + t[i].y*c[i].y + t[i].z*c[i].z + t[i].w*c[i].w;
    }
#pragma unroll
    for (int off = 1; off < 64; off <<= 1) {
        st += __shfl_xor(st, off);
        sc += __shfl_xor(sc, off);
        sd += __shfl_xor(sd, off);
    }
    const float invt = 1.0f / fmaxf(sqrtf(st), 1e-8f);
    const float invc = 1.0f / fmaxf(sqrtf(sc), 1e-8f);
#pragma unroll
    for (int i = 0; i < 3; ++i) {
        unsigned int wt = (unsigned int)__builtin_amdgcn_cvt_pk_fp8_f32(t[i].x * invt, t[i].y * invt, 0, false);
        wt = (unsigned int)__builtin_amdgcn_cvt_pk_fp8_f32(t[i].z * invt, t[i].w * invt, (int)wt, true);
        unsigned int wcq = (unsigned int)__builtin_amdgcn_cvt_pk_fp8_f32(c[i].x * invc, c[i].y * invc, 0, false);
        wcq = (unsigned int)__builtin_amdgcn_cvt_pk_fp8_f32(c[i].z * invc, c[i].w * invc, (int)wcq, true);
        *(unsigned int*)&tq[base + lane * 4 + i * 256] = wt;
        *(unsigned int*)&cq[base + lane * 4 + i * 256] = wcq;
    }
    if (lane == 0) sim[row] = sd * invt * invc;
}

// MX-scaled fp8 GEMM (unit scales): 128x128 tile, BK=128, 512 threads / 8 waves
// in a 2x4 grid (64x32 output per wave).
// Round 6 change: counted-vmcnt pipeline (T4) + raw s_barrier + setprio (T5).
// Rounds 4-5 proved (matching guide m99/m100/m233) that with __syncthreads'
// implicit vmcnt(0) drain, explicit double-buffering is a null: the 2-barrier
// lockstep structure itself costs ~3x the MFMA+BW time. Now the main loop
// NEVER drains vmcnt to 0:
//   per step t: ds_read frags(buf cur) ; lgkmcnt(0) ; s_barrier   <- reads done
//               issue DMA tile t+2 -> buf cur (overwrite safe)
//               setprio(1) ; 8x MFMA ; setprio(0)
//               s_waitcnt vmcnt(4)  <- tile t+1 landed, t+2 STAYS IN FLIGHT
//               s_barrier
// vmcnt counting: 4 global_load_lds per thread per tile, retired in issue
// order (m135); prologue pins group order with sched_barrier(0).
// LDS layout per buffer: [kc(4)][row(128)][32B], halves swizzled by (kc&1):
// conflict-free (verified SQ_LDS_BANK_CONFLICT = 0).
// LDS total 64 KB/block -> 2 blocks/CU; VGPR target <=128 (4 waves/SIMD).
__global__ __launch_bounds__(512, 4) void gemm_lse_kernel(
    const unsigned char* __restrict__ tq, const unsigned char* __restrict__ cq,
    float* __restrict__ rowsum, float* __restrict__ colsum) {
    __shared__ char ldsA[2][TILE * BK];   // 2 x 16 KB
    __shared__ char ldsB[2][TILE * BK];   // 2 x 16 KB

    const int tid = threadIdx.x;

    // XCD-banded swizzle: XCD x owns tile-rows [8x, 8x+8), sweeping columns.
    const int bid = blockIdx.x;
    const int xcd = bid & 7, idx = bid >> 3;
    const int tileCol = idx >> 3, rowInBand = idx & 7;
    const int rowBase = (xcd * 8 + rowInBand) * TILE;
    const int colBase = tileCol * TILE;

    const int wave = tid >> 6, lane = tid & 63;
    const int wr = wave >> 2, wc = wave & 3;        // 2x4 wave grid: 64 rows x 32 cols
    const int quad = lane >> 4, l16 = lane & 15;

    // Staging: 1024 16B chunks per tile; thread owns chunks tid, tid+512.
    // chunk p -> kc = p>>8, row = (p>>1)&127, phys-half = p&1,
    // logical-half = (p&1) ^ (kc&1). LDS dest is linear (wave-uniform+lane*16).
    int goff[2], p16[2];
#pragma unroll
    for (int i = 0; i < 2; ++i) {
        const int p  = tid + i * 512;
        const int kc = p >> 8;
        const int row = (p >> 1) & 127;
        const int hl  = (p & 1) ^ (kc & 1);
        goff[i] = row * DIM + kc * 32 + hl * 16;
        p16[i]  = p * 16;
    }
    const unsigned char* gA = tq + (size_t)rowBase * DIM;
    const unsigned char* gB = cq + (size_t)colBase * DIM;

    // Fragment addressing: lane (quad,l16) needs k-block kc=quad of its row;
    // physical half = logical half ^ (quad&1).
    const int sw = quad & 1;
    int aoff[4], boff[2];
#pragma unroll
    for (int mt = 0; mt < 4; ++mt) aoff[mt] = quad * 4096 + (wr * 64 + mt * 16 + l16) * 32;
#pragma unroll
    for (int nt = 0; nt < 2; ++nt) boff[nt] = quad * 4096 + (wc * 32 + nt * 16 + l16) * 32;

    f32x4 acc[4][2];
#pragma unroll
    for (int mt = 0; mt < 4; ++mt)
#pragma unroll
        for (int nt = 0; nt < 2; ++nt)
            acc[mt][nt] = (f32x4){0.f, 0.f, 0.f, 0.f};

    // Prologue: stage tiles 0 and 1 (issue order pinned so vmcnt counts map
    // to tiles), wait only for tile 0 (vmcnt(4): tile 1's 4 stay in flight).
#pragma unroll
    for (int i = 0; i < 2; ++i) {
        async16(gA + goff[i], &ldsA[0][p16[i]]);
        async16(gB + goff[i], &ldsB[0][p16[i]]);
    }
    __builtin_amdgcn_sched_barrier(0);
#pragma unroll
    for (int i = 0; i < 2; ++i) {
        async16(gA + goff[i] + BK, &ldsA[1][p16[i]]);
        async16(gB + goff[i] + BK, &ldsB[1][p16[i]]);
    }
    __builtin_amdgcn_sched_barrier(0);
    asm volatile("s_waitcnt vmcnt(4)" ::: "memory");
    __builtin_amdgcn_sched_barrier(0);
    __builtin_amdgcn_s_barrier();

#pragma unroll
    for (int t = 0; t < 6; ++t) {
        const int cur = t & 1;
        const char* A = ldsA[cur];
        const char* B = ldsB[cur];

        // Fragment reads for the whole K-tile (12 ds_read_b128, conflict-free).
        i32x8 bf[2], af[4];
#pragma unroll
        for (int nt = 0; nt < 2; ++nt) {
            i32x4 lo = *(const i32x4*)(B + boff[nt] + sw * 16);
            i32x4 hi = *(const i32x4*)(B + boff[nt] + (sw ^ 1) * 16);
            bf[nt] = __builtin_shufflevector(lo, hi, 0, 1, 2, 3, 4, 5, 6, 7);
        }
#pragma unroll
        for (int mt = 0; mt < 4; ++mt) {
            i32x4 lo = *(const i32x4*)(A + aoff[mt] + sw * 16);
            i32x4 hi = *(const i32x4*)(A + aoff[mt] + (sw ^ 1) * 16);
            af[mt] = __builtin_shufflevector(lo, hi, 0, 1, 2, 3, 4, 5, 6, 7);
        }

        if (t + 2 < 6) {
            // All my reads of buf[cur] complete...
            asm volatile("s_waitcnt lgkmcnt(0)" ::: "memory");
            __builtin_amdgcn_sched_barrier(0);
            // ...and everyone else's too: safe to overwrite buf[cur].
            __builtin_amdgcn_s_barrier();
            __builtin_amdgcn_sched_barrier(0);
            const int k0 = (t + 2) * BK;
#pragma unroll
            for (int i = 0; i < 2; ++i) {
                async16(gA + goff[i] + k0, &ldsA[cur][p16[i]]);
                async16(gB + goff[i] + k0, &ldsB[cur][p16[i]]);
            }
            __builtin_amdgcn_sched_barrier(0);
        }

        __builtin_amdgcn_s_setprio(1);
#pragma unroll
        for (int mt = 0; mt < 4; ++mt)
#pragma unroll
            for (int nt = 0; nt < 2; ++nt)
                acc[mt][nt] = __builtin_amdgcn_mfma_scale_f32_16x16x128_f8f6f4(
                    af[mt], bf[nt], acc[mt][nt], 0, 0, 0, 127, 0, 127);
        __builtin_amdgcn_s_setprio(0);

        if (t < 5) {
            // Wait for tile t+1 only (oldest 4 loads); tile t+2's 4 loads
            // remain in flight ACROSS the barrier (T4: never vmcnt(0) here).
            if (t <= 3) asm volatile("s_waitcnt vmcnt(4)" ::: "memory");
            else        asm volatile("s_waitcnt vmcnt(0)" ::: "memory");
            __builtin_amdgcn_sched_barrier(0);
            __builtin_amdgcn_s_barrier();
            __builtin_amdgcn_sched_barrier(0);
        }
    }

    // Epilogue. D layout: col = l16 (ctr idx), row = quad*4 + reg (text idx).
    float rp[4][4];   // [mt][reg] partials over this wave's 32 cols
    float cp[2];      // [nt] partials over this wave's 64 rows
#pragma unroll
    for (int mt = 0; mt < 4; ++mt)
#pragma unroll
        for (int r = 0; r < 4; ++r) rp[mt][r] = 0.f;
#pragma unroll
    for (int nt = 0; nt < 2; ++nt) cp[nt] = 0.f;

#pragma unroll
    for (int mt = 0; mt < 4; ++mt)
#pragma unroll
        for (int nt = 0; nt < 2; ++nt)
#pragma unroll
            for (int r = 0; r < 4; ++r) {
                const float e = __expf(acc[mt][nt][r]);   // S in [-1,1]: no max needed
                rp[mt][r] += e;
                cp[nt]    += e;
            }

#pragma unroll
    for (int mt = 0; mt < 4; ++mt)
#pragma unroll
        for (int r = 0; r < 4; ++r) {
            float v = rp[mt][r];
            v += __shfl_xor(v, 1);
            v += __shfl_xor(v, 2);
            v += __shfl_xor(v, 4);
            v += __shfl_xor(v, 8);
            rp[mt][r] = v;
        }
    if (l16 == 0) {
#pragma unroll
        for (int mt = 0; mt < 4; ++mt)
#pragma unroll
            for (int r = 0; r < 4; ++r)
                atomicAdd(&rowsum[rowBase + wr * 64 + mt * 16 + quad * 4 + r], rp[mt][r]);
    }
#pragma unroll
    for (int nt = 0; nt < 2; ++nt) {
        float v = cp[nt];
        v += __shfl_xor(v, 16);
        v += __shfl_xor(v, 32);
        if (quad == 0)
            atomicAdd(&colsum[colBase + wc * 32 + nt * 16 + l16], v);
    }
}

__global__ __launch_bounds__(1024) void finalize_kernel(
    const float* __restrict__ rowsum, const float* __restrict__ colsum,
    const float* __restrict__ sim, float* __restrict__ out) {
    const int tid = threadIdx.x;
    float acc = 0.f;
#pragma unroll
    for (int i = 0; i < 2; ++i) {
        const int j = (tid + i * 1024) * 4;
        float4 rs = *(const float4*)&rowsum[j];
        float4 cs = *(const float4*)&colsum[j];
        float4 sm = *(const float4*)&sim[j];
        acc += __logf(rs.x) + __logf(rs.y) + __logf(rs.z) + __logf(rs.w);
        acc += __logf(cs.x) + __logf(cs.y) + __logf(cs.z) + __logf(cs.w);
        acc -= 2.f * (sm.x + sm.y + sm.z + sm.w);
    }
#pragma unroll
    for (int off = 1; off < 64; off <<= 1) acc += __shfl_xor(acc, off);
    __shared__ float red[16];
    const int wave = tid >> 6, lane = tid & 63;
    if (lane == 0) red[wave] = acc;
    __syncthreads();
    if (tid == 0) {
        float s = 0.f;
#pragma unroll
        for (int w = 0; w < 16; ++w) s += red[w];
        out[0] = s / (float)BS;
    }
}

extern "C" void kernel_launch(void* const* d_in, const int* in_sizes, int n_in,
                              void* d_out, int out_size, void* d_ws, size_t ws_size,
                              hipStream_t stream) {
    const float* text = (const float*)d_in[0];
    const float* ctr  = (const float*)d_in[1];

    char* ws = (char*)d_ws;
    const size_t embBytes = (size_t)BS * DIM;   // fp8: 6,291,456 bytes each
    unsigned char* tq = (unsigned char*)ws;
    unsigned char* cq = (unsigned char*)(ws + embBytes);
    float* sim    = (float*)(ws + 2 * embBytes);
    float* rowsum = (float*)(ws + 2 * embBytes + BS * sizeof(float));
    float* colsum = (float*)(ws + 2 * embBytes + 2 * BS * sizeof(float));

    normalize_kernel<<<BS / 4, 256, 0, stream>>>(text, ctr, tq, cq, sim, rowsum, colsum);

    gemm_lse_kernel<<<(BS / TILE) * (BS / TILE), 512, 0, stream>>>(tq, cq, rowsum, colsum);

    finalize_kernel<<<1, 1024, 0, stream>>>(rowsum, colsum, sim, (float*)d_out);
}

// Round 3
// 187.076 us; speedup vs baseline: 1.0473x; 1.0473x over previous
//
#include <hip/hip_runtime.h>
#include <hip/hip_bf16.h>

#define BS   8192
#define DIM  768
#define TILE 128
#define BK   128   // one scaled-MFMA K per iteration; 6 iterations total

typedef float f32x4 __attribute__((ext_vector_type(4)));
typedef int   i32x4 __attribute__((ext_vector_type(4)));
typedef int   i32x8 __attribute__((ext_vector_type(8)));

__device__ __forceinline__ void async16(const void* g, void* l) {
    __builtin_amdgcn_global_load_lds(
        (const __attribute__((address_space(1))) unsigned int*)g,
        (__attribute__((address_space(3))) unsigned int*)l,
        16, 0, 0);
}

// One wave per row: L2-norm both embeddings, emit fp8 e4m3, diag sim in fp32.
// Blocks 0..63 also zero rowsum/colsum (replaces the hipMemsetAsync dispatch).
__global__ __launch_bounds__(256) void normalize_kernel(
    const float* __restrict__ text, const float* __restrict__ ctr,
    unsigned char* __restrict__ tq, unsigned char* __restrict__ cq,
    float* __restrict__ sim, float* __restrict__ rowsum, float* __restrict__ colsum) {
    if (blockIdx.x < 64) {
        const int i = blockIdx.x * 256 + threadIdx.x;   // covers 16384 = 2*BS
        rowsum[i] = 0.f;
        colsum[i] = 0.f;
    }
    const int lane = threadIdx.x & 63;
    const int row  = blockIdx.x * 4 + (threadIdx.x >> 6);
    const size_t base = (size_t)row * DIM;

    float4 t[3], c[3];
    float st = 0.f, sc = 0.f, sd = 0.f;
#pragma unroll
    for (int i = 0; i < 3; ++i) {
        t[i] = *(const float4*)&text[base + lane * 4 + i * 256];
        c[i] = *(const float4*)&ctr [base + lane * 4 + i * 256];
        st += t[i].x*t[i].x + t[i].y*t[i].y + t[i].z*t[i].z + t[i].w*t[i].w;
        sc += c[i].x*c[i].x + c[i].y*c[i].y + c[i].z*c[i].z + c[i].w*c[i].w;
        sd += t[i].x*c[i].x + t[i].y*c[i].y + t[i].z*c[i].z + t[i].w*c[i].w;
    }
#pragma unroll
    for (int off = 1; off < 64; off <<= 1) {
        st += __shfl_xor(st, off);
        sc += __shfl_xor(sc, off);
        sd += __shfl_xor(sd, off);
    }
    const float invt = 1.0f / fmaxf(sqrtf(st), 1e-8f);
    const float invc = 1.0f / fmaxf(sqrtf(sc), 1e-8f);
#pragma unroll
    for (int i = 0; i < 3; ++i) {
        unsigned int wt = (unsigned int)__builtin_amdgcn_cvt_pk_fp8_f32(t[i].x * invt, t[i].y * invt, 0, false);
        wt = (unsigned int)__builtin_amdgcn_cvt_pk_fp8_f32(t[i].z * invt, t[i].w * invt, (int)wt, true);
        unsigned int wcq = (unsigned int)__builtin_amdgcn_cvt_pk_fp8_f32(c[i].x * invc, c[i].y * invc, 0, false);
        wcq = (unsigned int)__builtin_amdgcn_cvt_pk_fp8_f32(c[i].z * invc, c[i].w * invc, (int)wcq, true);
        *(unsigned int*)&tq[base + lane * 4 + i * 256] = wt;
        *(unsigned int*)&cq[base + lane * 4 + i * 256] = wcq;
    }
    if (lane == 0) sim[row] = sd * invt * invc;
}

// MX-scaled fp8 GEMM (unit scales), round 7: replicate the m148 geometry.
// Evidence: rounds 5-6 proved intra-block pipelining (dbuf, counted vmcnt,
// setprio) is a NULL at this tile size -- all land at 118-120us / MfmaUtil
// 17.5%, reproducing guide m99/m100/m131-m141. The guide's m132 is literally
// our old config (BK=128 unroll, 64KB LDS, 2 blocks/CU -> 508 TF bf16-equiv),
// while m148 (128^2 tile, 256 threads / 4 waves / 4x4 acc per wave, 32KB
// single-buffered LDS, simple 2-barrier loop, 3-4 blocks/CU) hits 1628 TF
// MX-fp8. Mechanism (m114): the barrier drain is hidden by INTER-BLOCK
// overlap, which needs >=3 independent blocks/CU -- not by source pipelining.
// New geometry: 4 waves in 2x2 grid, each wave owns 64x64 (acc[4][4]);
// MFMA:ds_read ratio 1.0 (was 0.67); LDS read amplification 2x (was 3x);
// LDS 32KB/block -> 3-4 blocks/CU.
// LDS layout per buffer: [kc(4)][row(128)][32B], halves swizzled by (kc&1):
// conflict-free (verified SQ_LDS_BANK_CONFLICT = 0 in rounds 3-6).
__global__ __launch_bounds__(256, 3) void gemm_lse_kernel(
    const unsigned char* __restrict__ tq, const unsigned char* __restrict__ cq,
    float* __restrict__ rowsum, float* __restrict__ colsum) {
    __shared__ char ldsA[TILE * BK];   // 16 KB
    __shared__ char ldsB[TILE * BK];   // 16 KB

    const int tid = threadIdx.x;

    // XCD-banded swizzle: XCD x owns tile-rows [8x, 8x+8), sweeping columns.
    const int bid = blockIdx.x;
    const int xcd = bid & 7, idx = bid >> 3;
    const int tileCol = idx >> 3, rowInBand = idx & 7;
    const int rowBase = (xcd * 8 + rowInBand) * TILE;
    const int colBase = tileCol * TILE;

    const int wave = tid >> 6, lane = tid & 63;
    const int wr = wave >> 1, wc = wave & 1;        // 2x2 wave grid: 64x64 per wave
    const int quad = lane >> 4, l16 = lane & 15;

    // Staging: 1024 16B chunks per tile; thread owns chunks tid + i*256.
    // chunk p -> kc = p>>8, row = (p>>1)&127, phys-half = p&1,
    // logical-half = (p&1) ^ (kc&1). LDS dest is linear (wave-uniform+lane*16).
    int goff[4], p16[4];
#pragma unroll
    for (int i = 0; i < 4; ++i) {
        const int p  = tid + i * 256;
        const int kc = p >> 8;
        const int row = (p >> 1) & 127;
        const int hl  = (p & 1) ^ (kc & 1);
        goff[i] = row * DIM + kc * 32 + hl * 16;
        p16[i]  = p * 16;
    }
    const unsigned char* gA = tq + (size_t)rowBase * DIM;
    const unsigned char* gB = cq + (size_t)colBase * DIM;

    // Fragment addressing: lane (quad,l16) needs k-block kc=quad of its row;
    // physical half = logical half ^ (quad&1).
    const int sw = quad & 1;
    int aoff[4], boff[4];
#pragma unroll
    for (int mt = 0; mt < 4; ++mt) aoff[mt] = quad * 4096 + (wr * 64 + mt * 16 + l16) * 32;
#pragma unroll
    for (int nt = 0; nt < 4; ++nt) boff[nt] = quad * 4096 + (wc * 64 + nt * 16 + l16) * 32;

    f32x4 acc[4][4];
#pragma unroll
    for (int mt = 0; mt < 4; ++mt)
#pragma unroll
        for (int nt = 0; nt < 4; ++nt)
            acc[mt][nt] = (f32x4){0.f, 0.f, 0.f, 0.f};

    for (int t = 0; t < 6; ++t) {
        const int k0 = t * BK;
#pragma unroll
        for (int i = 0; i < 4; ++i) {
            async16(gA + goff[i] + k0, ldsA + p16[i]);
            async16(gB + goff[i] + k0, ldsB + p16[i]);
        }
        __syncthreads();

        i32x8 bf[4];
#pragma unroll
        for (int nt = 0; nt < 4; ++nt) {
            i32x4 lo = *(const i32x4*)(ldsB + boff[nt] + sw * 16);
            i32x4 hi = *(const i32x4*)(ldsB + boff[nt] + (sw ^ 1) * 16);
            bf[nt] = __builtin_shufflevector(lo, hi, 0, 1, 2, 3, 4, 5, 6, 7);
        }
#pragma unroll
        for (int mt = 0; mt < 4; ++mt) {
            i32x4 lo = *(const i32x4*)(ldsA + aoff[mt] + sw * 16);
            i32x4 hi = *(const i32x4*)(ldsA + aoff[mt] + (sw ^ 1) * 16);
            i32x8 af = __builtin_shufflevector(lo, hi, 0, 1, 2, 3, 4, 5, 6, 7);
#pragma unroll
            for (int nt = 0; nt < 4; ++nt)
                acc[mt][nt] = __builtin_amdgcn_mfma_scale_f32_16x16x128_f8f6f4(
                    af, bf[nt], acc[mt][nt], 0, 0, 0, 127, 0, 127);
        }
        __syncthreads();
    }

    // Epilogue. D layout: col = l16 (ctr idx), row = quad*4 + reg (text idx).
    float rp[4][4];   // [mt][reg] partials over this wave's 64 cols
    float cp[4];      // [nt] partials over this wave's 64 rows
#pragma unroll
    for (int mt = 0; mt < 4; ++mt)
#pragma unroll
        for (int r = 0; r < 4; ++r) rp[mt][r] = 0.f;
#pragma unroll
    for (int nt = 0; nt < 4; ++nt) cp[nt] = 0.f;

#pragma unroll
    for (int mt = 0; mt < 4; ++mt)
#pragma unroll
        for (int nt = 0; nt < 4; ++nt)
#pragma unroll
            for (int r = 0; r < 4; ++r) {
                const float e = __expf(acc[mt][nt][r]);   // S in [-1,1]: no max needed
                rp[mt][r] += e;
                cp[nt]    += e;
            }

#pragma unroll
    for (int mt = 0; mt < 4; ++mt)
#pragma unroll
        for (int r = 0; r < 4; ++r) {
            float v = rp[mt][r];
            v += __shfl_xor(v, 1);
            v += __shfl_xor(v, 2);
            v += __shfl_xor(v, 4);
            v += __shfl_xor(v, 8);
            rp[mt][r] = v;
        }
    if (l16 == 0) {
#pragma unroll
        for (int mt = 0; mt < 4; ++mt)
#pragma unroll
            for (int r = 0; r < 4; ++r)
                atomicAdd(&rowsum[rowBase + wr * 64 + mt * 16 + quad * 4 + r], rp[mt][r]);
    }
#pragma unroll
    for (int nt = 0; nt < 4; ++nt) {
        float v = cp[nt];
        v += __shfl_xor(v, 16);
        v += __shfl_xor(v, 32);
        if (quad == 0)
            atomicAdd(&colsum[colBase + wc * 64 + nt * 16 + l16], v);
    }
}

__global__ __launch_bounds__(1024) void finalize_kernel(
    const float* __restrict__ rowsum, const float* __restrict__ colsum,
    const float* __restrict__ sim, float* __restrict__ out) {
    const int tid = threadIdx.x;
    float acc = 0.f;
#pragma unroll
    for (int i = 0; i < 2; ++i) {
        const int j = (tid + i * 1024) * 4;
        float4 rs = *(const float4*)&rowsum[j];
        float4 cs = *(const float4*)&colsum[j];
        float4 sm = *(const float4*)&sim[j];
        acc += __logf(rs.x) + __logf(rs.y) + __logf(rs.z) + __logf(rs.w);
        acc += __logf(cs.x) + __logf(cs.y) + __logf(cs.z) + __logf(cs.w);
        acc -= 2.f * (sm.x + sm.y + sm.z + sm.w);
    }
#pragma unroll
    for (int off = 1; off < 64; off <<= 1) acc += __shfl_xor(acc, off);
    __shared__ float red[16];
    const int wave = tid >> 6, lane = tid & 63;
    if (lane == 0) red[wave] = acc;
    __syncthreads();
    if (tid == 0) {
        float s = 0.f;
#pragma unroll
        for (int w = 0; w < 16; ++w) s += red[w];
        out[0] = s / (float)BS;
    }
}

extern "C" void kernel_launch(void* const* d_in, const int* in_sizes, int n_in,
                              void* d_out, int out_size, void* d_ws, size_t ws_size,
                              hipStream_t stream) {
    const float* text = (const float*)d_in[0];
    const float* ctr  = (const float*)d_in[1];

    char* ws = (char*)d_ws;
    const size_t embBytes = (size_t)BS * DIM;   // fp8: 6,291,456 bytes each
    unsigned char* tq = (unsigned char*)ws;
    unsigned char* cq = (unsigned char*)(ws + embBytes);
    float* sim    = (float*)(ws + 2 * embBytes);
    float* rowsum = (float*)(ws + 2 * embBytes + BS * sizeof(float));
    float* colsum = (float*)(ws + 2 * embBytes + 2 * BS * sizeof(float));

    normalize_kernel<<<BS / 4, 256, 0, stream>>>(text, ctr, tq, cq, sim, rowsum, colsum);

    gemm_lse_kernel<<<(BS / TILE) * (BS / TILE), 256, 0, stream>>>(tq, cq, rowsum, colsum);

    finalize_kernel<<<1, 1024, 0, stream>>>(rowsum, colsum, sim, (float*)d_out);
}

// Round 4
// 169.402 us; speedup vs baseline: 1.1566x; 1.1043x over previous
//
#include <hip/hip_runtime.h>
#include <hip/hip_bf16.h>

#define BS   8192
#define DIM  768
#define BM   256
#define BK   128   // one scaled-MFMA K per tile; 6 tiles total

typedef float f32x4 __attribute__((ext_vector_type(4)));
typedef int   i32x4 __attribute__((ext_vector_type(4)));
typedef int   i32x8 __attribute__((ext_vector_type(8)));

__device__ __forceinline__ void async16(const void* g, void* l) {
    __builtin_amdgcn_global_load_lds(
        (const __attribute__((address_space(1))) unsigned int*)g,
        (__attribute__((address_space(3))) unsigned int*)l,
        16, 0, 0);
}

// One wave per row: L2-norm both embeddings, emit fp8 e4m3, diag sim in fp32.
// Blocks 0..63 also zero rowsum/colsum (replaces the hipMemsetAsync dispatch).
__global__ __launch_bounds__(256) void normalize_kernel(
    const float* __restrict__ text, const float* __restrict__ ctr,
    unsigned char* __restrict__ tq, unsigned char* __restrict__ cq,
    float* __restrict__ sim, float* __restrict__ rowsum, float* __restrict__ colsum) {
    if (blockIdx.x < 64) {
        const int i = blockIdx.x * 256 + threadIdx.x;   // covers 16384 = 2*BS
        rowsum[i] = 0.f;
        colsum[i] = 0.f;
    }
    const int lane = threadIdx.x & 63;
    const int row  = blockIdx.x * 4 + (threadIdx.x >> 6);
    const size_t base = (size_t)row * DIM;

    float4 t[3], c[3];
    float st = 0.f, sc = 0.f, sd = 0.f;
#pragma unroll
    for (int i = 0; i < 3; ++i) {
        t[i] = *(const float4*)&text[base + lane * 4 + i * 256];
        c[i] = *(const float4*)&ctr [base + lane * 4 + i * 256];
        st += t[i].x*t[i].x + t[i].y*t[i].y + t[i].z*t[i].z + t[i].w*t[i].w;
        sc += c[i].x*c[i].x + c[i].y*c[i].y + c[i].z*c[i].z + c[i].w*c[i].w;
        sd += t[i].x*c[i].x + t[i].y*c[i].y + t[i].z*c[i].z + t[i].w*c[i].w;
    }
#pragma unroll
    for (int off = 1; off < 64; off <<= 1) {
        st += __shfl_xor(st, off);
        sc += __shfl_xor(sc, off);
        sd += __shfl_xor(sd, off);
    }
    const float invt = 1.0f / fmaxf(sqrtf(st), 1e-8f);
    const float invc = 1.0f / fmaxf(sqrtf(sc), 1e-8f);
#pragma unroll
    for (int i = 0; i < 3; ++i) {
        unsigned int wt = (unsigned int)__builtin_amdgcn_cvt_pk_fp8_f32(t[i].x * invt, t[i].y * invt, 0, false);
        wt = (unsigned int)__builtin_amdgcn_cvt_pk_fp8_f32(t[i].z * invt, t[i].w * invt, (int)wt, true);
        unsigned int wcq = (unsigned int)__builtin_amdgcn_cvt_pk_fp8_f32(c[i].x * invc, c[i].y * invc, 0, false);
        wcq = (unsigned int)__builtin_amdgcn_cvt_pk_fp8_f32(c[i].z * invc, c[i].w * invc, (int)wcq, true);
        *(unsigned int*)&tq[base + lane * 4 + i * 256] = wt;
        *(unsigned int*)&cq[base + lane * 4 + i * 256] = wcq;
    }
    if (lane == 0) sim[row] = sd * invt * invc;
}

// MX-scaled fp8 GEMM (unit scales), round 8: 256x256 tile, 4-phase deep
// pipeline (guide T3+T4+T5). Evidence so far: every 2-phase lockstep variant
// (8-wave/64KB, counted-vmcnt, 4-wave/32KB m148-geometry) lands at 960-1030
// TF-equiv, matching the guide's regime-gate: 2-phase caps; the 8-phase
// interleave is the gate for T4/T5 gains (+28-73%, m196/m198/m218).
// Geometry: 512 thr / 8 waves (2x4), per-wave 128x64 = acc[8][4] (128 VGPR).
// LDS 2 x (32KB A + 32KB B) = 128 KB -> 1 block/CU; latency hiding is
// INTRA-block: per K-tile 4 phases, each {ds_read next A-pair || stage
// quarter of tile t+1 || lgkmcnt(4) || setprio(1) 8xMFMA setprio(0)}.
// Boundary: lgkmcnt(0)+barrier (reads done, buf[cur] safe to overwrite),
// issue t+2 quarter-0 into buf[cur], s_waitcnt vmcnt(2) (tile t+1 landed,
// t+2.Q0 STAYS IN FLIGHT - never drain to 0 mid-loop), barrier.
// Steady-state outstanding at each boundary = 10 loads, waits to 2.
// LDS layout per buffer: [kc(4)][row(256)][32B], halves swizzled by (kc&1):
// conflict-free (same read/write pattern as rounds 3-7, measured 0 conflicts).
__global__ __launch_bounds__(512, 2) void gemm_lse_kernel(
    const unsigned char* __restrict__ tq, const unsigned char* __restrict__ cq,
    float* __restrict__ rowsum, float* __restrict__ colsum) {
    __shared__ char ldsA[2][BM * BK];   // 2 x 32 KB
    __shared__ char ldsB[2][BM * BK];   // 2 x 32 KB

    const int tid = threadIdx.x;

    // XCD-banded swizzle: XCD x owns tile-rows [4x, 4x+4), sweeping columns.
    const int bid = blockIdx.x;              // 1024 blocks = 32x32 tiles
    const int xcd = bid & 7, idx = bid >> 3;
    const int tileCol = idx >> 2, rowInBand = idx & 3;
    const int rowBase = (xcd * 4 + rowInBand) * BM;
    const int colBase = tileCol * BM;

    const int wave = tid >> 6, lane = tid & 63;
    const int wr = wave >> 2, wc = wave & 3;   // 2x4 wave grid: 128x64 per wave
    const int quad = lane >> 4, l16 = lane & 15;

    // Staging: 2048 16B chunks per operand tile; thread owns chunk tid+i*512
    // (quarter i). chunk p -> kc = p>>9, row = (p>>1)&255,
    // logical-half = (p&1) ^ (kc&1). LDS dest linear (wave-uniform + lane*16).
    int goff[4], p16[4];
#pragma unroll
    for (int i = 0; i < 4; ++i) {
        const int p  = tid + i * 512;
        const int kc = p >> 9;
        const int row = (p >> 1) & 255;
        const int hl  = (p & 1) ^ (kc & 1);
        goff[i] = row * DIM + kc * 32 + hl * 16;
        p16[i]  = p * 16;
    }
    const unsigned char* gA = tq + (size_t)rowBase * DIM;
    const unsigned char* gB = cq + (size_t)colBase * DIM;

#define STAGE(buf, t, i)                                            \
    do {                                                            \
        async16(gA + goff[i] + (t) * BK, &ldsA[buf][p16[i]]);       \
        async16(gB + goff[i] + (t) * BK, &ldsB[buf][p16[i]]);       \
    } while (0)

    // Fragment addressing: lane (quad,l16) needs k-block kc=quad of its row;
    // physical half = logical half ^ (quad&1).
    const int sw = quad & 1;
    int aoff[8], boff[4];
#pragma unroll
    for (int mt = 0; mt < 8; ++mt) aoff[mt] = quad * 8192 + (wr * 128 + mt * 16 + l16) * 32;
#pragma unroll
    for (int nt = 0; nt < 4; ++nt) boff[nt] = quad * 8192 + (wc * 64 + nt * 16 + l16) * 32;

#define RD_A(dst, mt, buf)                                                     \
    do {                                                                       \
        i32x4 lo = *(const i32x4*)(ldsA[buf] + aoff[mt] + sw * 16);            \
        i32x4 hi = *(const i32x4*)(ldsA[buf] + aoff[mt] + (sw ^ 1) * 16);      \
        dst = __builtin_shufflevector(lo, hi, 0, 1, 2, 3, 4, 5, 6, 7);         \
    } while (0)
#define RD_B(dst, nt, buf)                                                     \
    do {                                                                       \
        i32x4 lo = *(const i32x4*)(ldsB[buf] + boff[nt] + sw * 16);            \
        i32x4 hi = *(const i32x4*)(ldsB[buf] + boff[nt] + (sw ^ 1) * 16);      \
        dst = __builtin_shufflevector(lo, hi, 0, 1, 2, 3, 4, 5, 6, 7);         \
    } while (0)
#define MFMA8(a0, a1, m0, m1)                                                  \
    do {                                                                       \
        acc[m0][0] = __builtin_amdgcn_mfma_scale_f32_16x16x128_f8f6f4(a0, bf0, acc[m0][0], 0, 0, 0, 127, 0, 127); \
        acc[m0][1] = __builtin_amdgcn_mfma_scale_f32_16x16x128_f8f6f4(a0, bf1, acc[m0][1], 0, 0, 0, 127, 0, 127); \
        acc[m0][2] = __builtin_amdgcn_mfma_scale_f32_16x16x128_f8f6f4(a0, bf2, acc[m0][2], 0, 0, 0, 127, 0, 127); \
        acc[m0][3] = __builtin_amdgcn_mfma_scale_f32_16x16x128_f8f6f4(a0, bf3, acc[m0][3], 0, 0, 0, 127, 0, 127); \
        acc[m1][0] = __builtin_amdgcn_mfma_scale_f32_16x16x128_f8f6f4(a1, bf0, acc[m1][0], 0, 0, 0, 127, 0, 127); \
        acc[m1][1] = __builtin_amdgcn_mfma_scale_f32_16x16x128_f8f6f4(a1, bf1, acc[m1][1], 0, 0, 0, 127, 0, 127); \
        acc[m1][2] = __builtin_amdgcn_mfma_scale_f32_16x16x128_f8f6f4(a1, bf2, acc[m1][2], 0, 0, 0, 127, 0, 127); \
        acc[m1][3] = __builtin_amdgcn_mfma_scale_f32_16x16x128_f8f6f4(a1, bf3, acc[m1][3], 0, 0, 0, 127, 0, 127); \
    } while (0)
#define SBAR()  __builtin_amdgcn_sched_barrier(0)

    f32x4 acc[8][4];
#pragma unroll
    for (int mt = 0; mt < 8; ++mt)
#pragma unroll
        for (int nt = 0; nt < 4; ++nt)
            acc[mt][nt] = (f32x4){0.f, 0.f, 0.f, 0.f};

    // Prologue: stage tile 0 fully (8 loads) + tile 1 quarter 0 (2 loads);
    // wait vmcnt(2): tile 0 landed, t1.Q0 in flight.
    STAGE(0, 0, 0); STAGE(0, 0, 1); STAGE(0, 0, 2); STAGE(0, 0, 3);
    SBAR();
    STAGE(1, 1, 0);
    SBAR();
    asm volatile("s_waitcnt vmcnt(2)" ::: "memory");
    SBAR();
    __builtin_amdgcn_s_barrier();

#pragma unroll
    for (int t = 0; t < 6; ++t) {
        const int cur = t & 1;
        i32x8 bf0, bf1, bf2, bf3, aE0, aE1, aO0, aO1;

        // Pre-phase reads: all B (8 b128) + A pair0 (4 b128).
        RD_B(bf0, 0, cur); RD_B(bf1, 1, cur); RD_B(bf2, 2, cur); RD_B(bf3, 3, cur);
        RD_A(aE0, 0, cur); RD_A(aE1, 1, cur);

        // ph0: prefetch A pair1; stage Q1(t+1); wait(4); MFMA pair0.
        RD_A(aO0, 2, cur); RD_A(aO1, 3, cur);
        if (t < 5) STAGE(cur ^ 1, t + 1, 1);
        asm volatile("s_waitcnt lgkmcnt(4)" ::: "memory");
        SBAR();
        __builtin_amdgcn_s_setprio(1);
        MFMA8(aE0, aE1, 0, 1);
        __builtin_amdgcn_s_setprio(0);

        // ph1: prefetch A pair2; stage Q2(t+1); wait(4); MFMA pair1.
        RD_A(aE0, 4, cur); RD_A(aE1, 5, cur);
        if (t < 5) STAGE(cur ^ 1, t + 1, 2);
        asm volatile("s_waitcnt lgkmcnt(4)" ::: "memory");
        SBAR();
        __builtin_amdgcn_s_setprio(1);
        MFMA8(aO0, aO1, 2, 3);
        __builtin_amdgcn_s_setprio(0);

        // ph2: prefetch A pair3; stage Q3(t+1); wait(4); MFMA pair2.
        RD_A(aO0, 6, cur); RD_A(aO1, 7, cur);
        if (t < 5) STAGE(cur ^ 1, t + 1, 3);
        asm volatile("s_waitcnt lgkmcnt(4)" ::: "memory");
        SBAR();
        __builtin_amdgcn_s_setprio(1);
        MFMA8(aE0, aE1, 4, 5);
        __builtin_amdgcn_s_setprio(0);

        // ph3: wait(0); MFMA pair3.
        asm volatile("s_waitcnt lgkmcnt(0)" ::: "memory");
        SBAR();
        __builtin_amdgcn_s_setprio(1);
        MFMA8(aO0, aO1, 6, 7);
        __builtin_amdgcn_s_setprio(0);

        // Boundary: mid-barrier (everyone's reads of buf[cur] done) ->
        // issue t+2.Q0 into buf[cur]; counted vmcnt; barrier (buf[cur^1]
        // fully staged for all waves).
        if (t < 5) {
            __builtin_amdgcn_s_barrier();
            SBAR();
            if (t < 4) {
                STAGE(cur, t + 2, 0);
                SBAR();
                asm volatile("s_waitcnt vmcnt(2)" ::: "memory");
            } else {
                asm volatile("s_waitcnt vmcnt(0)" ::: "memory");
            }
            SBAR();
            __builtin_amdgcn_s_barrier();
        }
    }

    // Epilogue. D layout: col = l16 (ctr idx), row = quad*4 + reg (text idx).
    float rp[8][4];   // [mt][reg] partials over this wave's 64 cols
    float cp[4];      // [nt] partials over this wave's 128 rows
#pragma unroll
    for (int mt = 0; mt < 8; ++mt)
#pragma unroll
        for (int r = 0; r < 4; ++r) rp[mt][r] = 0.f;
#pragma unroll
    for (int nt = 0; nt < 4; ++nt) cp[nt] = 0.f;

#pragma unroll
    for (int mt = 0; mt < 8; ++mt)
#pragma unroll
        for (int nt = 0; nt < 4; ++nt)
#pragma unroll
            for (int r = 0; r < 4; ++r) {
                const float e = __expf(acc[mt][nt][r]);   // S in [-1,1]: no max needed
                rp[mt][r] += e;
                cp[nt]    += e;
            }

#pragma unroll
    for (int mt = 0; mt < 8; ++mt)
#pragma unroll
        for (int r = 0; r < 4; ++r) {
            float v = rp[mt][r];
            v += __shfl_xor(v, 1);
            v += __shfl_xor(v, 2);
            v += __shfl_xor(v, 4);
            v += __shfl_xor(v, 8);
            rp[mt][r] = v;
        }
    if (l16 == 0) {
#pragma unroll
        for (int mt = 0; mt < 8; ++mt)
#pragma unroll
            for (int r = 0; r < 4; ++r)
                atomicAdd(&rowsum[rowBase + wr * 128 + mt * 16 + quad * 4 + r], rp[mt][r]);
    }
#pragma unroll
    for (int nt = 0; nt < 4; ++nt) {
        float v = cp[nt];
        v += __shfl_xor(v, 16);
        v += __shfl_xor(v, 32);
        if (quad == 0)
            atomicAdd(&colsum[colBase + wc * 64 + nt * 16 + l16], v);
    }
}

__global__ __launch_bounds__(1024) void finalize_kernel(
    const float* __restrict__ rowsum, const float* __restrict__ colsum,
    const float* __restrict__ sim, float* __restrict__ out) {
    const int tid = threadIdx.x;
    float acc = 0.f;
#pragma unroll
    for (int i = 0; i < 2; ++i) {
        const int j = (tid + i * 1024) * 4;
        float4 rs = *(const float4*)&rowsum[j];
        float4 cs = *(const float4*)&colsum[j];
        float4 sm = *(const float4*)&sim[j];
        acc += __logf(rs.x) + __logf(rs.y) + __logf(rs.z) + __logf(rs.w);
        acc += __logf(cs.x) + __logf(cs.y) + __logf(cs.z) + __logf(cs.w);
        acc -= 2.f * (sm.x + sm.y + sm.z + sm.w);
    }
#pragma unroll
    for (int off = 1; off < 64; off <<= 1) acc += __shfl_xor(acc, off);
    __shared__ float red[16];
    const int wave = tid >> 6, lane = tid & 63;
    if (lane == 0) red[wave] = acc;
    __syncthreads();
    if (tid == 0) {
        float s = 0.f;
#pragma unroll
        for (int w = 0; w < 16; ++w) s += red[w];
        out[0] = s / (float)BS;
    }
}

extern "C" void kernel_launch(void* const* d_in, const int* in_sizes, int n_in,
                              void* d_out, int out_size, void* d_ws, size_t ws_size,
                              hipStream_t stream) {
    const float* text = (const float*)d_in[0];
    const float* ctr  = (const float*)d_in[1];

    char* ws = (char*)d_ws;
    const size_t embBytes = (size_t)BS * DIM;   // fp8: 6,291,456 bytes each
    unsigned char* tq = (unsigned char*)ws;
    unsigned char* cq = (unsigned char*)(ws + embBytes);
    float* sim    = (float*)(ws + 2 * embBytes);
    float* rowsum = (float*)(ws + 2 * embBytes + BS * sizeof(float));
    float* colsum = (float*)(ws + 2 * embBytes + 2 * BS * sizeof(float));

    normalize_kernel<<<BS / 4, 256, 0, stream>>>(text, ctr, tq, cq, sim, rowsum, colsum);

    gemm_lse_kernel<<<(BS / BM) * (BS / BM), 512, 0, stream>>>(tq, cq, rowsum, colsum);

    finalize_kernel<<<1, 1024, 0, stream>>>(rowsum, colsum, sim, (float*)d_out);
}